// Round 2
// baseline (19650.948 us; speedup 1.0000x reference)
//
#include <hip/hip_runtime.h>
#include <hip/hip_cooperative_groups.h>
#include <cmath>

namespace cg = cooperative_groups;

#define TT 512
#define BB 64
#define HH 512
#define II 128
#define KSTRIDE 1024   // LDS k-stride per row-pair (max of 640, 1024)

typedef float v2f __attribute__((ext_vector_type(2)));

// dynamic LDS floats: wlds 8*KSTRIDE*2 =16384 | part 16*8*64 =8192 |
// gates 16*64 =1024 | cst 4*64 =256 | bsum 16
#define SMEM_FLOATS (16384 + 8192 + 1024 + 256 + 16)
#define SMEM_BYTES  (SMEM_FLOATS * 4)

__device__ __forceinline__ float sigm(float v) { return 1.0f / (1.0f + expf(-v)); }

// ---------------------------------------------------------------------------
// Transpose x: [64][512][128] (b,t,k) -> xT: [512][128][64] (t,k,b)
// ---------------------------------------------------------------------------
__global__ __launch_bounds__(1024) void k_transpose_x(const float* __restrict__ x,
                                                      float* __restrict__ xT) {
  __shared__ float tile[64][65];
  const int t  = blockIdx.x >> 1;
  const int k0 = (blockIdx.x & 1) << 6;
  const int lk = threadIdx.x & 63;
  const int lb = threadIdx.x >> 6;
#pragma unroll
  for (int bp = 0; bp < 64; bp += 16) {
    const int b = bp + lb;
    tile[lk][b] = x[((size_t)b * TT + t) * II + k0 + lk];
  }
  __syncthreads();
  const int b2  = threadIdx.x & 63;
  const int kk0 = threadIdx.x >> 6;
#pragma unroll
  for (int kp = 0; kp < 64; kp += 16) {
    const int kk = kp + kk0;
    xT[((size_t)t * II + k0 + kk) * BB + b2] = tile[kk][b2];
  }
}

// ---------------------------------------------------------------------------
// Persistent pipelined 2-layer LSTM. Blocks 0..127: layer0 (t=s);
// blocks 128..255: layer1 (t=s-1). 513 phases, grid.sync() per phase.
// Weights live in LDS (staged once, pair-interleaved for v_pk_fma_f32).
// c-state lives in LDS. Only h crosses blocks (global ring buffers).
// Thread map: tid = kseg(3b) | rg(1b) | b(6b); 8 rows/thread = 4 row-pairs.
// ---------------------------------------------------------------------------
__global__ __launch_bounds__(1024, 4) void k_lstm_persist(
    const float* __restrict__ xT,
    const float* __restrict__ W_ih0, const float* __restrict__ W_hh0,
    const float* __restrict__ b_ih0, const float* __restrict__ b_hh0,
    const float* __restrict__ W_ih1, const float* __restrict__ W_hh1,
    const float* __restrict__ b_ih1, const float* __restrict__ b_hh1,
    float* __restrict__ h0ring, float* __restrict__ h1ring)
{
  extern __shared__ float smem[];
  float* wlds  = smem;            // [pair8][KSTRIDE][2]
  float* part  = wlds + 16384;    // [row16][kseg8][b64]
  float* gates = part + 8192;     // [row16][b64]
  float* cst   = gates + 1024;    // [u4][b64]
  float* bsum  = cst + 256;       // [16]

  const int bid = blockIdx.x;
  const int L   = bid >> 7;
  const int ub  = (bid & 127) << 2;   // 4 hidden units per block
  const int tid = threadIdx.x;

  const float* WA = L ? W_ih1 : W_ih0;
  const float* WB = L ? W_hh1 : W_hh0;
  const int KA = L ? HH : II;

  // ---- one-time: stage weights (pair-interleaved) + bias sums + c=0 ----
  const int ktot = KA + HH;
  for (int idx = tid; idx < 16 * ktot; idx += 1024) {
    const int lr = idx / ktot;
    const int k  = idx - lr * ktot;
    const int u = lr >> 2, q = lr & 3;
    const int G = q * HH + ub + u;           // i,f,g,o chunk order
    const float w = (k < KA) ? WA[G * KA + k] : WB[G * HH + (k - KA)];
    wlds[((lr >> 1) * KSTRIDE + k) * 2 + (lr & 1)] = w;
  }
  if (tid < 16) {
    const int u = tid >> 2, q = tid & 3;
    const int G = q * HH + ub + u;
    bsum[tid] = L ? (b_ih1[G] + b_hh1[G]) : (b_ih0[G] + b_hh0[G]);
  }
  if (tid < 256) cst[tid] = 0.0f;
  __syncthreads();

  const int kseg = tid >> 7;
  const int rg   = (tid >> 6) & 1;
  const int b    = tid & 63;

  cg::grid_group grid = cg::this_grid();

  for (int s = 0; s <= TT; ++s) {
    const int t = L ? (s - 1) : s;
    if (t >= 0 && t < TT) {
      const bool first = (t == 0);
      const float* srcA = L ? (h0ring + ((s - 1) & 1) * (HH * BB))
                            : (xT + (size_t)t * (II * BB));
      const float* srcB = L ? (h1ring + (s & 1) * (HH * BB))
                            : (h0ring + ((s - 1) & 1) * (HH * BB));

      v2f acc[4];
#pragma unroll
      for (int j = 0; j < 4; ++j) acc[j] = (v2f){0.0f, 0.0f};

      { // ---- A part (x for L0, h0[t] for L1) ----
        const int kn = KA >> 3;
        const int k0 = kseg * kn;
        const float* sA = srcA + b;
        for (int kk = 0; kk < kn; kk += 4) {
          const int k = k0 + kk;
          const float v0 = sA[(k + 0) * BB];
          const float v1 = sA[(k + 1) * BB];
          const float v2 = sA[(k + 2) * BB];
          const float v3 = sA[(k + 3) * BB];
#pragma unroll
          for (int j = 0; j < 4; ++j) {
            const float* wp = wlds + (((rg << 2) + j) * KSTRIDE + k) * 2;
            const float4 wa = *(const float4*)(wp);
            const float4 wb = *(const float4*)(wp + 4);
            acc[j] = __builtin_elementwise_fma((v2f){wa.x, wa.y}, (v2f){v0, v0}, acc[j]);
            acc[j] = __builtin_elementwise_fma((v2f){wa.z, wa.w}, (v2f){v1, v1}, acc[j]);
            acc[j] = __builtin_elementwise_fma((v2f){wb.x, wb.y}, (v2f){v2, v2}, acc[j]);
            acc[j] = __builtin_elementwise_fma((v2f){wb.z, wb.w}, (v2f){v3, v3}, acc[j]);
          }
        }
      }
      if (!first) { // ---- B part (recurrent h; zero at t==0) ----
        const int k0 = kseg * 64;
        const float* sB = srcB + b;
        for (int kk = 0; kk < 64; kk += 4) {
          const int k = k0 + kk;
          const float v0 = sB[(k + 0) * BB];
          const float v1 = sB[(k + 1) * BB];
          const float v2 = sB[(k + 2) * BB];
          const float v3 = sB[(k + 3) * BB];
#pragma unroll
          for (int j = 0; j < 4; ++j) {
            const float* wp = wlds + (((rg << 2) + j) * KSTRIDE + KA + k) * 2;
            const float4 wa = *(const float4*)(wp);
            const float4 wb = *(const float4*)(wp + 4);
            acc[j] = __builtin_elementwise_fma((v2f){wa.x, wa.y}, (v2f){v0, v0}, acc[j]);
            acc[j] = __builtin_elementwise_fma((v2f){wa.z, wa.w}, (v2f){v1, v1}, acc[j]);
            acc[j] = __builtin_elementwise_fma((v2f){wb.x, wb.y}, (v2f){v2, v2}, acc[j]);
            acc[j] = __builtin_elementwise_fma((v2f){wb.z, wb.w}, (v2f){v3, v3}, acc[j]);
          }
        }
      }

      // ---- reduce ksegs -> gates (lanes = b everywhere: conflict-free) ----
#pragma unroll
      for (int j = 0; j < 4; ++j) {
        part[(((rg << 3) + 2 * j + 0) * 8 + kseg) * 64 + b] = acc[j].x;
        part[(((rg << 3) + 2 * j + 1) * 8 + kseg) * 64 + b] = acc[j].y;
      }
      __syncthreads();
      {
        const int row = tid >> 6;
        const int bb  = tid & 63;
        float g = 0.0f;
#pragma unroll
        for (int ks = 0; ks < 8; ++ks) g += part[(row * 8 + ks) * 64 + bb];
        gates[row * 64 + bb] = g + bsum[row];
      }
      __syncthreads();

      if (tid < 256) { // ---- cell update: one thread per (unit, batch) ----
        const int u = tid >> 6, bb = tid & 63;
        const float gi = sigm(gates[((u << 2) + 0) * 64 + bb]);
        const float gf = sigm(gates[((u << 2) + 1) * 64 + bb]);
        const float gg = tanhf(gates[((u << 2) + 2) * 64 + bb]);
        const float go = sigm(gates[((u << 2) + 3) * 64 + bb]);
        const float cold = first ? 0.0f : cst[u * 64 + bb];
        const float cn = gf * cold + gi * gg;
        const float hn = go * tanhf(cn);
        cst[u * 64 + bb] = cn;
        float* hdst = (L ? h1ring : h0ring) + (t & 1) * (HH * BB);
        hdst[(ub + u) * 64 + bb] = hn;
      }
    }
    grid.sync();
  }
}

// ---------------------------------------------------------------------------
// out[b] = sum_j h1_last[j][b] * Wl[j] + bl[0]
// ---------------------------------------------------------------------------
__global__ __launch_bounds__(512) void k_final(const float* __restrict__ h1last,
                                               const float* __restrict__ Wl,
                                               const float* __restrict__ bl,
                                               float* __restrict__ out) {
  __shared__ float red[8][64];
  const int jg = threadIdx.x >> 6, b = threadIdx.x & 63;
  float a = 0.0f;
  for (int jj = 0; jj < 64; ++jj) {
    const int j = (jg << 6) + jj;
    a += h1last[j * BB + b] * Wl[j];
  }
  red[jg][b] = a;
  __syncthreads();
  if (threadIdx.x < 64) {
    float s = bl[0];
#pragma unroll
    for (int g = 0; g < 8; ++g) s += red[g][threadIdx.x];
    out[threadIdx.x] = s;
  }
}

extern "C" void kernel_launch(void* const* d_in, const int* in_sizes, int n_in,
                              void* d_out, int out_size, void* d_ws, size_t ws_size,
                              hipStream_t stream) {
  (void)in_sizes; (void)n_in; (void)out_size; (void)ws_size;
  const float* x     = (const float*)d_in[0];
  const float* W_ih0 = (const float*)d_in[1];
  const float* W_hh0 = (const float*)d_in[2];
  const float* b_ih0 = (const float*)d_in[3];
  const float* b_hh0 = (const float*)d_in[4];
  const float* W_ih1 = (const float*)d_in[5];
  const float* W_hh1 = (const float*)d_in[6];
  const float* b_ih1 = (const float*)d_in[7];
  const float* b_hh1 = (const float*)d_in[8];
  const float* Wl    = (const float*)d_in[9];
  const float* bl    = (const float*)d_in[10];
  float* out = (float*)d_out;

  float* ws     = (float*)d_ws;
  float* xT     = ws;                         // 512*128*64
  float* h0ring = xT + (size_t)TT * II * BB;  // 2*512*64
  float* h1ring = h0ring + 2 * HH * BB;       // 2*512*64

  k_transpose_x<<<1024, 1024, 0, stream>>>(x, xT);

  hipFuncSetAttribute((const void*)k_lstm_persist,
                      hipFuncAttributeMaxDynamicSharedMemorySize, SMEM_BYTES);

  void* args[] = {
    (void*)&xT,
    (void*)&W_ih0, (void*)&W_hh0, (void*)&b_ih0, (void*)&b_hh0,
    (void*)&W_ih1, (void*)&W_hh1, (void*)&b_ih1, (void*)&b_hh1,
    (void*)&h0ring, (void*)&h1ring,
  };
  hipLaunchCooperativeKernel((void*)k_lstm_persist, dim3(256), dim3(1024),
                             args, SMEM_BYTES, stream);

  k_final<<<1, 512, 0, stream>>>(h1ring + HH * BB, Wl, bl, out);
}

// Round 3
// 14160.797 us; speedup vs baseline: 1.3877x; 1.3877x over previous
//
#include <hip/hip_runtime.h>
#include <cmath>

#define TT 512
#define BB 64
#define HH 512
#define II 128
#define NBLK 256
#define KSTRIDE 1024   // LDS k-stride per row-pair (max of 640, 1024)

typedef float v2f __attribute__((ext_vector_type(2)));

// dynamic LDS floats: wlds 8*KSTRIDE*2 =16384 | part 16*8*64 =8192 |
// gates 16*64 =1024 | cst 4*64 =256 | bsum 16
#define SMEM_FLOATS (16384 + 8192 + 1024 + 256 + 16)
#define SMEM_BYTES  (SMEM_FLOATS * 4)

__device__ __forceinline__ float sigm(float v) { return 1.0f / (1.0f + expf(-v)); }
__device__ __forceinline__ unsigned umin2(unsigned a, unsigned b) { return a < b ? a : b; }

// ---------------------------------------------------------------------------
// Transpose x: [64][512][128] (b,t,k) -> xT: [512][128][64] (t,k,b)
// ---------------------------------------------------------------------------
__global__ __launch_bounds__(1024) void k_transpose_x(const float* __restrict__ x,
                                                      float* __restrict__ xT) {
  __shared__ float tile[64][65];
  const int t  = blockIdx.x >> 1;
  const int k0 = (blockIdx.x & 1) << 6;
  const int lk = threadIdx.x & 63;
  const int lb = threadIdx.x >> 6;
#pragma unroll
  for (int bp = 0; bp < 64; bp += 16) {
    const int b = bp + lb;
    tile[lk][b] = x[((size_t)b * TT + t) * II + k0 + lk];
  }
  __syncthreads();
  const int b2  = threadIdx.x & 63;
  const int kk0 = threadIdx.x >> 6;
#pragma unroll
  for (int kp = 0; kp < 64; kp += 16) {
    const int kk = kp + kk0;
    xT[((size_t)t * II + k0 + kk) * BB + b2] = tile[kk][b2];
  }
}

__global__ void k_init_flags(unsigned* flags) { flags[threadIdx.x] = 0u; }

// ---------------------------------------------------------------------------
// Persistent pipelined 2-layer LSTM with hand-rolled flag barrier.
// Blocks 0..127: layer0 (t=s); blocks 128..255: layer1 (t=s-1). 513 phases.
// flags[bid] = number of completed phases (monotonic). Phase s waits for all
// flags >= s (full barrier), which preserves ring-depth-2 safety:
// a block entering phase s knows every block finished phase s-1 (reads incl.).
// L0's x-part runs BEFORE the wait (no cross-phase dependency) to hide latency.
// ---------------------------------------------------------------------------
__global__ __launch_bounds__(1024, 1) void k_lstm_persist(
    const float* __restrict__ xT,
    const float* __restrict__ W_ih0, const float* __restrict__ W_hh0,
    const float* __restrict__ b_ih0, const float* __restrict__ b_hh0,
    const float* __restrict__ W_ih1, const float* __restrict__ W_hh1,
    const float* __restrict__ b_ih1, const float* __restrict__ b_hh1,
    float* __restrict__ h0ring, float* __restrict__ h1ring,
    unsigned* __restrict__ flags)
{
  extern __shared__ float smem[];
  float* wlds  = smem;            // [pair8][KSTRIDE][2]
  float* part  = wlds + 16384;    // [row16][kseg8][b64]
  float* gates = part + 8192;     // [row16][b64]
  float* cst   = gates + 1024;    // [u4][b64]
  float* bsum  = cst + 256;       // [16]

  const int bid = blockIdx.x;
  const int L   = bid >> 7;
  const int ub  = (bid & 127) << 2;   // 4 hidden units per block
  const int tid = threadIdx.x;

  const float* WA = L ? W_ih1 : W_ih0;
  const float* WB = L ? W_hh1 : W_hh0;
  const int KA = L ? HH : II;

  // ---- one-time: stage weights (pair-interleaved) + bias sums + c=0 ----
  const int ktot = KA + HH;
  for (int idx = tid; idx < 16 * ktot; idx += 1024) {
    const int lr = idx / ktot;
    const int k  = idx - lr * ktot;
    const int u = lr >> 2, q = lr & 3;
    const int G = q * HH + ub + u;           // i,f,g,o chunk order
    const float w = (k < KA) ? WA[G * KA + k] : WB[G * HH + (k - KA)];
    wlds[((lr >> 1) * KSTRIDE + k) * 2 + (lr & 1)] = w;
  }
  if (tid < 16) {
    const int u = tid >> 2, q = tid & 3;
    const int G = q * HH + ub + u;
    bsum[tid] = L ? (b_ih1[G] + b_hh1[G]) : (b_ih0[G] + b_hh0[G]);
  }
  if (tid < 256) cst[tid] = 0.0f;
  __syncthreads();

  const int kseg = tid >> 7;
  const int rg   = (tid >> 6) & 1;
  const int b    = tid & 63;

  for (int s = 0; s <= TT; ++s) {
    const int t = L ? (s - 1) : s;
    const bool active = (t >= 0 && t < TT);
    const bool first  = (t == 0);

    v2f acc[4];
    if (active) {
#pragma unroll
      for (int j = 0; j < 4; ++j) acc[j] = (v2f){0.0f, 0.0f};

      if (L == 0) {  // ---- x-part BEFORE the wait: no cross-phase dep ----
        const int kn = II >> 3;
        const int k0 = kseg * kn;
        const float* sA = xT + (size_t)t * (II * BB) + b;
        for (int kk = 0; kk < kn; kk += 4) {
          const int k = k0 + kk;
          const float v0 = sA[(k + 0) * BB];
          const float v1 = sA[(k + 1) * BB];
          const float v2 = sA[(k + 2) * BB];
          const float v3 = sA[(k + 3) * BB];
#pragma unroll
          for (int j = 0; j < 4; ++j) {
            const float* wp = wlds + (((rg << 2) + j) * KSTRIDE + k) * 2;
            const float4 wa = *(const float4*)(wp);
            const float4 wb = *(const float4*)(wp + 4);
            acc[j] = __builtin_elementwise_fma((v2f){wa.x, wa.y}, (v2f){v0, v0}, acc[j]);
            acc[j] = __builtin_elementwise_fma((v2f){wa.z, wa.w}, (v2f){v1, v1}, acc[j]);
            acc[j] = __builtin_elementwise_fma((v2f){wb.x, wb.y}, (v2f){v2, v2}, acc[j]);
            acc[j] = __builtin_elementwise_fma((v2f){wb.z, wb.w}, (v2f){v3, v3}, acc[j]);
          }
        }
      }
    }

    // ---- wait: all blocks published phase s-1 (skip at s==0) ----
    if (s > 0) {
      if (tid < 64) {
        const unsigned tgt = (unsigned)s;
        for (;;) {
          const unsigned m0 = __hip_atomic_load(flags + tid,       __ATOMIC_RELAXED, __HIP_MEMORY_SCOPE_AGENT);
          const unsigned m1 = __hip_atomic_load(flags + tid +  64, __ATOMIC_RELAXED, __HIP_MEMORY_SCOPE_AGENT);
          const unsigned m2 = __hip_atomic_load(flags + tid + 128, __ATOMIC_RELAXED, __HIP_MEMORY_SCOPE_AGENT);
          const unsigned m3 = __hip_atomic_load(flags + tid + 192, __ATOMIC_RELAXED, __HIP_MEMORY_SCOPE_AGENT);
          const unsigned mn = umin2(umin2(m0, m1), umin2(m2, m3));
          if (__all(mn >= tgt)) break;
          __builtin_amdgcn_s_sleep(1);
        }
        __threadfence();   // acquire: invalidate stale L1/L2 h lines
      }
      __syncthreads();
    }

    if (active) {
      if (L == 1) {  // ---- A-part for L1: h0[s-1] (just became safe) ----
        const int kn = HH >> 3;
        const int k0 = kseg * kn;
        const float* sA = h0ring + ((s - 1) & 1) * (HH * BB) + b;
        for (int kk = 0; kk < kn; kk += 4) {
          const int k = k0 + kk;
          const float v0 = sA[(k + 0) * BB];
          const float v1 = sA[(k + 1) * BB];
          const float v2 = sA[(k + 2) * BB];
          const float v3 = sA[(k + 3) * BB];
#pragma unroll
          for (int j = 0; j < 4; ++j) {
            const float* wp = wlds + (((rg << 2) + j) * KSTRIDE + k) * 2;
            const float4 wa = *(const float4*)(wp);
            const float4 wb = *(const float4*)(wp + 4);
            acc[j] = __builtin_elementwise_fma((v2f){wa.x, wa.y}, (v2f){v0, v0}, acc[j]);
            acc[j] = __builtin_elementwise_fma((v2f){wa.z, wa.w}, (v2f){v1, v1}, acc[j]);
            acc[j] = __builtin_elementwise_fma((v2f){wb.x, wb.y}, (v2f){v2, v2}, acc[j]);
            acc[j] = __builtin_elementwise_fma((v2f){wb.z, wb.w}, (v2f){v3, v3}, acc[j]);
          }
        }
      }
      if (!first) {  // ---- B-part: recurrent h (zero at t==0) ----
        const float* sB = (L ? (h1ring + (s & 1) * (HH * BB))
                             : (h0ring + ((s - 1) & 1) * (HH * BB))) + b;
        const int k0 = kseg * 64;
        for (int kk = 0; kk < 64; kk += 4) {
          const int k = k0 + kk;
          const float v0 = sB[(k + 0) * BB];
          const float v1 = sB[(k + 1) * BB];
          const float v2 = sB[(k + 2) * BB];
          const float v3 = sB[(k + 3) * BB];
#pragma unroll
          for (int j = 0; j < 4; ++j) {
            const float* wp = wlds + (((rg << 2) + j) * KSTRIDE + KA + k) * 2;
            const float4 wa = *(const float4*)(wp);
            const float4 wb = *(const float4*)(wp + 4);
            acc[j] = __builtin_elementwise_fma((v2f){wa.x, wa.y}, (v2f){v0, v0}, acc[j]);
            acc[j] = __builtin_elementwise_fma((v2f){wa.z, wa.w}, (v2f){v1, v1}, acc[j]);
            acc[j] = __builtin_elementwise_fma((v2f){wb.x, wb.y}, (v2f){v2, v2}, acc[j]);
            acc[j] = __builtin_elementwise_fma((v2f){wb.z, wb.w}, (v2f){v3, v3}, acc[j]);
          }
        }
      }

      // ---- reduce ksegs -> gates (lanes = b everywhere: conflict-free) ----
#pragma unroll
      for (int j = 0; j < 4; ++j) {
        part[(((rg << 3) + 2 * j + 0) * 8 + kseg) * 64 + b] = acc[j].x;
        part[(((rg << 3) + 2 * j + 1) * 8 + kseg) * 64 + b] = acc[j].y;
      }
      __syncthreads();
      {
        const int row = tid >> 6;
        const int bb  = tid & 63;
        float g = 0.0f;
#pragma unroll
        for (int ks = 0; ks < 8; ++ks) g += part[(row * 8 + ks) * 64 + bb];
        gates[row * 64 + bb] = g + bsum[row];
      }
      __syncthreads();

      if (tid < 256) {  // ---- cell update: one thread per (unit, batch) ----
        const int u = tid >> 6, bb = tid & 63;
        const float gi = sigm(gates[((u << 2) + 0) * 64 + bb]);
        const float gf = sigm(gates[((u << 2) + 1) * 64 + bb]);
        const float gg = tanhf(gates[((u << 2) + 2) * 64 + bb]);
        const float go = sigm(gates[((u << 2) + 3) * 64 + bb]);
        const float cold = first ? 0.0f : cst[u * 64 + bb];
        const float cn = gf * cold + gi * gg;
        const float hn = go * tanhf(cn);
        cst[u * 64 + bb] = cn;
        float* hdst = (L ? h1ring : h0ring) + (t & 1) * (HH * BB);
        hdst[(ub + u) * 64 + bb] = hn;
      }
      __syncthreads();  // all waves' h stores drained (vmcnt) before publish
    }

    // ---- publish: this block completed phase s ----
    if (tid == 0) {
      __threadfence();  // release: flush dirty h lines to coherent point
      __hip_atomic_store(flags + bid, (unsigned)(s + 1),
                         __ATOMIC_RELAXED, __HIP_MEMORY_SCOPE_AGENT);
    }
  }
}

// ---------------------------------------------------------------------------
// out[b] = sum_j h1_last[j][b] * Wl[j] + bl[0]
// ---------------------------------------------------------------------------
__global__ __launch_bounds__(512) void k_final(const float* __restrict__ h1last,
                                               const float* __restrict__ Wl,
                                               const float* __restrict__ bl,
                                               float* __restrict__ out) {
  __shared__ float red[8][64];
  const int jg = threadIdx.x >> 6, b = threadIdx.x & 63;
  float a = 0.0f;
  for (int jj = 0; jj < 64; ++jj) {
    const int j = (jg << 6) + jj;
    a += h1last[j * BB + b] * Wl[j];
  }
  red[jg][b] = a;
  __syncthreads();
  if (threadIdx.x < 64) {
    float s = bl[0];
#pragma unroll
    for (int g = 0; g < 8; ++g) s += red[g][threadIdx.x];
    out[threadIdx.x] = s;
  }
}

extern "C" void kernel_launch(void* const* d_in, const int* in_sizes, int n_in,
                              void* d_out, int out_size, void* d_ws, size_t ws_size,
                              hipStream_t stream) {
  (void)in_sizes; (void)n_in; (void)out_size; (void)ws_size;
  const float* x     = (const float*)d_in[0];
  const float* W_ih0 = (const float*)d_in[1];
  const float* W_hh0 = (const float*)d_in[2];
  const float* b_ih0 = (const float*)d_in[3];
  const float* b_hh0 = (const float*)d_in[4];
  const float* W_ih1 = (const float*)d_in[5];
  const float* W_hh1 = (const float*)d_in[6];
  const float* b_ih1 = (const float*)d_in[7];
  const float* b_hh1 = (const float*)d_in[8];
  const float* Wl    = (const float*)d_in[9];
  const float* bl    = (const float*)d_in[10];
  float* out = (float*)d_out;

  float* ws       = (float*)d_ws;
  float* xT       = ws;                         // 512*128*64
  float* h0ring   = xT + (size_t)TT * II * BB;  // 2*512*64
  float* h1ring   = h0ring + 2 * HH * BB;       // 2*512*64
  unsigned* flags = (unsigned*)(h1ring + 2 * HH * BB);  // 256 u32

  k_transpose_x<<<1024, 1024, 0, stream>>>(x, xT);
  k_init_flags<<<1, NBLK, 0, stream>>>(flags);

  hipFuncSetAttribute((const void*)k_lstm_persist,
                      hipFuncAttributeMaxDynamicSharedMemorySize, SMEM_BYTES);

  void* args[] = {
    (void*)&xT,
    (void*)&W_ih0, (void*)&W_hh0, (void*)&b_ih0, (void*)&b_hh0,
    (void*)&W_ih1, (void*)&W_hh1, (void*)&b_ih1, (void*)&b_hh1,
    (void*)&h0ring, (void*)&h1ring, (void*)&flags,
  };
  // Cooperative launch kept ONLY for the co-residency guarantee; sync is ours.
  hipLaunchCooperativeKernel((void*)k_lstm_persist, dim3(NBLK), dim3(1024),
                             args, SMEM_BYTES, stream);

  k_final<<<1, 512, 0, stream>>>(h1ring + HH * BB, Wl, bl, out);
}

// Round 10
// 11276.647 us; speedup vs baseline: 1.7426x; 1.2558x over previous
//
#include <hip/hip_runtime.h>
#include <cmath>

#define TT 512
#define BB 64
#define HH 512
#define II 128
#define NBLK 256

typedef float v2f __attribute__((ext_vector_type(2)));
__device__ __forceinline__ v2f fma2(v2f a, v2f b, v2f c) { return __builtin_elementwise_fma(a, b, c); }

// dynamic LDS floats: wlds 16*1024 =16384 | part 16*16*64 =16384 |
// gates 16*64 =1024 | cst 256 | bsum 16   => ~133 KB
#define SMEM_FLOATS (16384 + 16384 + 1024 + 256 + 16)
#define SMEM_BYTES  (SMEM_FLOATS * 4)

__device__ __forceinline__ float sigm(float v) { return 1.0f / (1.0f + expf(-v)); }
__device__ __forceinline__ unsigned umin2(unsigned a, unsigned b) { return a < b ? a : b; }

// One k-slice: 16 weights (rows 0..15) from LDS (wave-uniform broadcast),
// 8 v_pk_fma_f32. acc[j] covers rows (2j, 2j+1).
__device__ __forceinline__ void step(const float* wk, float v, v2f (&acc)[8]) {
  const float4* wp = (const float4*)wk;
  const float4 w0 = wp[0], w1 = wp[1], w2 = wp[2], w3 = wp[3];
  const v2f vb = (v2f){v, v};
  acc[0] = fma2((v2f){w0.x, w0.y}, vb, acc[0]);
  acc[1] = fma2((v2f){w0.z, w0.w}, vb, acc[1]);
  acc[2] = fma2((v2f){w1.x, w1.y}, vb, acc[2]);
  acc[3] = fma2((v2f){w1.z, w1.w}, vb, acc[3]);
  acc[4] = fma2((v2f){w2.x, w2.y}, vb, acc[4]);
  acc[5] = fma2((v2f){w2.z, w2.w}, vb, acc[5]);
  acc[6] = fma2((v2f){w3.x, w3.y}, vb, acc[6]);
  acc[7] = fma2((v2f){w3.z, w3.w}, vb, acc[7]);
}

// Span of kn k's starting at k0: PLAIN C++ loads (compiler-managed waitcnts —
// no hand vmcnt counting; sound under register spilling). 4-deep v staging.
__device__ __forceinline__ void span(const float* __restrict__ src,
                                     const float* __restrict__ wbase,
                                     int k0, int kn, int b, v2f (&acc)[8]) {
  for (int kk = 0; kk < kn; kk += 4) {
    const int k = k0 + kk;
    const float v0 = src[(k + 0) * BB + b];
    const float v1 = src[(k + 1) * BB + b];
    const float v2 = src[(k + 2) * BB + b];
    const float v3 = src[(k + 3) * BB + b];
    step(wbase + (size_t)(k + 0) * 16, v0, acc);
    step(wbase + (size_t)(k + 1) * 16, v1, acc);
    step(wbase + (size_t)(k + 2) * 16, v2, acc);
    step(wbase + (size_t)(k + 3) * 16, v3, acc);
  }
}

// ---------------------------------------------------------------------------
// Transpose x: [64][512][128] (b,t,k) -> xT: [512][128][64] (t,k,b)
// ---------------------------------------------------------------------------
__global__ __launch_bounds__(1024) void k_transpose_x(const float* __restrict__ x,
                                                      float* __restrict__ xT) {
  __shared__ float tile[64][65];
  const int t  = blockIdx.x >> 1;
  const int k0 = (blockIdx.x & 1) << 6;
  const int lk = threadIdx.x & 63;
  const int lb = threadIdx.x >> 6;
#pragma unroll
  for (int bp = 0; bp < 64; bp += 16) {
    const int b = bp + lb;
    tile[lk][b] = x[((size_t)b * TT + t) * II + k0 + lk];
  }
  __syncthreads();
  const int b2  = threadIdx.x & 63;
  const int kk0 = threadIdx.x >> 6;
#pragma unroll
  for (int kp = 0; kp < 64; kp += 16) {
    const int kk = kp + kk0;
    xT[((size_t)t * II + k0 + kk) * BB + b2] = tile[kk][b2];
  }
}

__global__ void k_init_flags(unsigned* flags) { flags[threadIdx.x] = 0u; }

// ---------------------------------------------------------------------------
// Persistent pipelined 2-layer LSTM.
// DATA PATH: 100% compiler-generated memory ops (no inline asm, no counted
//   vmcnt) — the rounds-4..9 hand pipeline was unsound under VGPR spilling
//   (scratch ops count in vmcnt, breaking hand-counted waits).
// SYNC: round-3's PROVEN protocol verbatim — spin(relaxed agent) ->
//   __threadfence -> barrier; barrier -> tid0 __threadfence -> relaxed flag.
//   One delta vs round 3: h stores are agent-scope atomic stores
//   (write-through) so L2 holds no dirty ws data -> release wbl2 is cheap.
// Thread map: tid = kseg(4b) | b(6b); each thread: all 16 rows, K/16 k's
//   (validated arithmetically by rounds 5-9's near-correct outputs).
// ---------------------------------------------------------------------------
__global__ __launch_bounds__(1024, 1) void k_lstm_persist(
    const float* __restrict__ xT,
    const float* __restrict__ W_ih0, const float* __restrict__ W_hh0,
    const float* __restrict__ b_ih0, const float* __restrict__ b_hh0,
    const float* __restrict__ W_ih1, const float* __restrict__ W_hh1,
    const float* __restrict__ b_ih1, const float* __restrict__ b_hh1,
    float* __restrict__ h0ring, float* __restrict__ h1ring,
    unsigned* __restrict__ flags)
{
  extern __shared__ float smem[];
  float* wlds  = smem;            // [k up to 1024][16 rows] k-major
  float* part  = wlds + 16384;    // [row16][kseg16][b64]
  float* gates = part + 16384;    // [row16][b64]
  float* cst   = gates + 1024;    // [u4][b64]
  float* bsum  = cst + 256;       // [16]

  const int bid = blockIdx.x;
  const int L   = bid >> 7;
  const int ub  = (bid & 127) << 2;   // 4 hidden units per block
  const int tid = threadIdx.x;

  const float* WA = L ? W_ih1 : W_ih0;
  const float* WB = L ? W_hh1 : W_hh0;
  const int KA = L ? HH : II;

  // ---- one-time: stage weights k-major + bias sums + c=0 ----
  const int ktot = KA + HH;
  for (int idx = tid; idx < 16 * ktot; idx += 1024) {
    const int k  = idx >> 4;
    const int lr = idx & 15;
    const int u = lr >> 2, q = lr & 3;
    const int G = q * HH + ub + u;           // i,f,g,o chunk order
    wlds[idx] = (k < KA) ? WA[G * KA + k] : WB[G * HH + (k - KA)];
  }
  if (tid < 16) {
    const int u = tid >> 2, q = tid & 3;
    const int G = q * HH + ub + u;
    bsum[tid] = L ? (b_ih1[G] + b_hh1[G]) : (b_ih0[G] + b_hh0[G]);
  }
  if (tid < 256) cst[tid] = 0.0f;
  __syncthreads();

  const int kseg = tid >> 6;   // 0..15
  const int b    = tid & 63;

  for (int s = 0; s <= TT; ++s) {
    const int t = L ? (s - 1) : s;
    const bool active = (t >= 0 && t < TT);
    const bool first  = (t == 0);

    v2f acc[8];
#pragma unroll
    for (int j = 0; j < 8; ++j) acc[j] = (v2f){0.0f, 0.0f};

    // ---- L0 x-part BEFORE the wait (x immutable; no cross-phase dep) ----
    if (active && L == 0) {
      span(xT + (size_t)t * (II * BB), wlds, kseg * (II / 16), II / 16, b, acc);
    }

    // ---- wait: all blocks published phase s-1; then acquire fence ----
    if (s > 0) {
      if (tid < 64) {
        const unsigned tgt = (unsigned)s;
        for (;;) {
          const unsigned m0 = __hip_atomic_load(flags + tid,       __ATOMIC_RELAXED, __HIP_MEMORY_SCOPE_AGENT);
          const unsigned m1 = __hip_atomic_load(flags + tid +  64, __ATOMIC_RELAXED, __HIP_MEMORY_SCOPE_AGENT);
          const unsigned m2 = __hip_atomic_load(flags + tid + 128, __ATOMIC_RELAXED, __HIP_MEMORY_SCOPE_AGENT);
          const unsigned m3 = __hip_atomic_load(flags + tid + 192, __ATOMIC_RELAXED, __HIP_MEMORY_SCOPE_AGENT);
          const unsigned mn = umin2(umin2(m0, m1), umin2(m2, m3));
          if (__all(mn >= tgt)) break;
          __builtin_amdgcn_s_sleep(1);
        }
        __threadfence();   // proven acquire (round 3): invalidate stale lines
      }
      __syncthreads();
    }

    if (active) {
      if (L == 0) {
        if (!first) {  // B-part: h0[s-1] @ parity (s-1)&1
          span(h0ring + (size_t)((s - 1) & 1) * (HH * BB), wlds + (size_t)II * 16,
               kseg * 32, 32, b, acc);
        }
      } else {
        // A-part: h0[s-1] @ parity (s-1)&1
        span(h0ring + (size_t)((s - 1) & 1) * (HH * BB), wlds,
             kseg * 32, 32, b, acc);
        if (!first) {  // B-part: h1[s-2] @ parity s&1
          span(h1ring + (size_t)(s & 1) * (HH * BB), wlds + (size_t)HH * 16,
               kseg * 32, 32, b, acc);
        }
      }

      // ---- reduce 16 ksegs -> gates (lanes = b: conflict-free) ----
#pragma unroll
      for (int j = 0; j < 4; ++j) {
        part[(((j << 2) + 0) * 16 + kseg) * 64 + b] = acc[(j << 1)].x;
        part[(((j << 2) + 1) * 16 + kseg) * 64 + b] = acc[(j << 1)].y;
        part[(((j << 2) + 2) * 16 + kseg) * 64 + b] = acc[(j << 1) + 1].x;
        part[(((j << 2) + 3) * 16 + kseg) * 64 + b] = acc[(j << 1) + 1].y;
      }
      __syncthreads();
      {
        const int row = tid >> 6;
        const int bb  = tid & 63;
        float g = 0.0f;
#pragma unroll
        for (int ks = 0; ks < 16; ++ks) g += part[(row * 16 + ks) * 64 + bb];
        gates[row * 64 + bb] = g + bsum[row];
      }
      __syncthreads();

      if (tid < 256) {  // cell update; h via agent-scope write-through store
        const int u = tid >> 6, bb = tid & 63;
        const float gi = sigm(gates[((u << 2) + 0) * 64 + bb]);
        const float gf = sigm(gates[((u << 2) + 1) * 64 + bb]);
        const float gg = tanhf(gates[((u << 2) + 2) * 64 + bb]);
        const float go = sigm(gates[((u << 2) + 3) * 64 + bb]);
        const float cold = first ? 0.0f : cst[u * 64 + bb];
        const float cn = gf * cold + gi * gg;
        const float hn = go * tanhf(cn);
        cst[u * 64 + bb] = cn;
        float* hdst = (L ? h1ring : h0ring) + (size_t)(t & 1) * (HH * BB);
        __hip_atomic_store(hdst + (ub + u) * 64 + bb, hn,
                           __ATOMIC_RELAXED, __HIP_MEMORY_SCOPE_AGENT);
      }
    }

    // barrier drains each wave's stores (vmcnt 0); then proven release publish
    __syncthreads();
    if (tid == 0) {
      __threadfence();   // proven release (round 3); cheap: L2 holds no dirty ws
      __hip_atomic_store(flags + bid, (unsigned)(s + 1),
                         __ATOMIC_RELAXED, __HIP_MEMORY_SCOPE_AGENT);
    }
  }
}

// ---------------------------------------------------------------------------
// out[b] = sum_j h1_last[j][b] * Wl[j] + bl[0]
// ---------------------------------------------------------------------------
__global__ __launch_bounds__(512) void k_final(const float* __restrict__ h1last,
                                               const float* __restrict__ Wl,
                                               const float* __restrict__ bl,
                                               float* __restrict__ out) {
  __shared__ float red[8][64];
  const int jg = threadIdx.x >> 6, b = threadIdx.x & 63;
  float a = 0.0f;
  for (int jj = 0; jj < 64; ++jj) {
    const int j = (jg << 6) + jj;
    a += h1last[j * BB + b] * Wl[j];
  }
  red[jg][b] = a;
  __syncthreads();
  if (threadIdx.x < 64) {
    float s = bl[0];
#pragma unroll
    for (int g = 0; g < 8; ++g) s += red[g][threadIdx.x];
    out[threadIdx.x] = s;
  }
}

extern "C" void kernel_launch(void* const* d_in, const int* in_sizes, int n_in,
                              void* d_out, int out_size, void* d_ws, size_t ws_size,
                              hipStream_t stream) {
  (void)in_sizes; (void)n_in; (void)out_size; (void)ws_size;
  const float* x     = (const float*)d_in[0];
  const float* W_ih0 = (const float*)d_in[1];
  const float* W_hh0 = (const float*)d_in[2];
  const float* b_ih0 = (const float*)d_in[3];
  const float* b_hh0 = (const float*)d_in[4];
  const float* W_ih1 = (const float*)d_in[5];
  const float* W_hh1 = (const float*)d_in[6];
  const float* b_ih1 = (const float*)d_in[7];
  const float* b_hh1 = (const float*)d_in[8];
  const float* Wl    = (const float*)d_in[9];
  const float* bl    = (const float*)d_in[10];
  float* out = (float*)d_out;

  float* ws       = (float*)d_ws;
  float* xT       = ws;                         // 512*128*64
  float* h0ring   = xT + (size_t)TT * II * BB;  // 2*512*64
  float* h1ring   = h0ring + 2 * HH * BB;       // 2*512*64
  unsigned* flags = (unsigned*)(h1ring + 2 * HH * BB);  // 256 u32

  k_transpose_x<<<1024, 1024, 0, stream>>>(x, xT);
  k_init_flags<<<1, NBLK, 0, stream>>>(flags);

  hipFuncSetAttribute((const void*)k_lstm_persist,
                      hipFuncAttributeMaxDynamicSharedMemorySize, SMEM_BYTES);

  void* args[] = {
    (void*)&xT,
    (void*)&W_ih0, (void*)&W_hh0, (void*)&b_ih0, (void*)&b_hh0,
    (void*)&W_ih1, (void*)&W_hh1, (void*)&b_ih1, (void*)&b_hh1,
    (void*)&h0ring, (void*)&h1ring, (void*)&flags,
  };
  // Cooperative launch kept ONLY for the co-residency guarantee; sync is ours.
  hipLaunchCooperativeKernel((void*)k_lstm_persist, dim3(NBLK), dim3(1024),
                             args, SMEM_BYTES, stream);

  // h1[T-1] lives at ring parity (T-1)&1 == 1
  k_final<<<1, 512, 0, stream>>>(h1ring + HH * BB, Wl, bl, out);
}